// Round 8
// baseline (1123.786 us; speedup 1.0000x reference)
//
#include <hip/hip_runtime.h>
#include <math.h>

typedef unsigned short ushort_t;
typedef __attribute__((ext_vector_type(8))) __bf16 bf16x8;
typedef __attribute__((ext_vector_type(4))) float floatx4;

#define B_    256
#define I_    1152
#define J_    10
#define DIN_  8
#define DOUT_ 16
#define K_    (I_*DIN_)     // 9216
#define N_    (J_*DOUT_)    // 160
#define NSPLIT 8
#define KCHUNK (K_/NSPLIT)  // 1152
#define KSTEPS (KCHUNK/32)  // 36
#define NBLK   512          // persistent grid: 2 blocks/CU guaranteed by launch_bounds
#define NTHR   (NBLK*256)   // 131072 threads, 2048 waves

static __device__ __forceinline__ ushort_t f2bf(float f) {
    unsigned int u = __float_as_uint(f);
    u += 0x7fffu + ((u >> 16) & 1u);     // RNE
    return (ushort_t)(u >> 16);
}
static __device__ __forceinline__ float bf2f(ushort_t h) {
    return __uint_as_float(((unsigned int)h) << 16);
}

// Device-scope grid barrier (counter + generation). All NBLK blocks are
// co-resident: LDS 5.8KB, launch_bounds(256,2) caps VGPR at 128 -> >=2 blocks/CU.
static __device__ __forceinline__ void grid_barrier(unsigned* count, unsigned* gen)
{
    __syncthreads();
    if (threadIdx.x == 0) {
        unsigned g = __hip_atomic_load(gen, __ATOMIC_RELAXED, __HIP_MEMORY_SCOPE_AGENT);
        __threadfence();   // publish this block's writes (device scope)
        unsigned arrived = __hip_atomic_fetch_add(count, 1u, __ATOMIC_ACQ_REL,
                                                  __HIP_MEMORY_SCOPE_AGENT);
        if (arrived == NBLK - 1) {
            __hip_atomic_store(count, 0u, __ATOMIC_RELAXED, __HIP_MEMORY_SCOPE_AGENT);
            __hip_atomic_store(gen, g + 1u, __ATOMIC_RELEASE, __HIP_MEMORY_SCOPE_AGENT);
        } else {
            while (__hip_atomic_load(gen, __ATOMIC_ACQUIRE,
                                     __HIP_MEMORY_SCOPE_AGENT) == g)
                __builtin_amdgcn_s_sleep(1);
        }
        __threadfence();   // acquire others' writes
    }
    __syncthreads();
}

__global__ __launch_bounds__(256, 2)
void capsule_fused_kernel(const float* __restrict__ x, const float* __restrict__ W,
                          float* __restrict__ s_out,
                          ushort_t* __restrict__ Xt_hi, ushort_t* __restrict__ Xt_lo,
                          ushort_t* __restrict__ Sbt_hi, ushort_t* __restrict__ Sbt_lo,
                          float* __restrict__ P, float* __restrict__ blog,
                          unsigned* __restrict__ bar)
{
    const int tid = threadIdx.x;
    const int blk = blockIdx.x;
    const int gthread = blk * 256 + tid;
    const int lane = tid & 63;
    const int waveid = blk * 4 + (tid >> 6);   // 0..2047
    unsigned* bar_count = bar;
    unsigned* bar_gen   = bar + 1;

    __shared__ float c_lds[144 * J_];          // 5.76 KB

    // ---- Phase P: Xt hi/lo transpose-split + zero blog ----
    for (int t = gthread; t < B_ * K_ / 4; t += NTHR) {   // 589824 items
        int k  = t >> 6;
        int b0 = (t & 63) * 4;
        ushort4 hi, lo;
        float v;
        v = x[(size_t)(b0 + 0) * K_ + k]; hi.x = f2bf(v); lo.x = f2bf(v - bf2f(hi.x));
        v = x[(size_t)(b0 + 1) * K_ + k]; hi.y = f2bf(v); lo.y = f2bf(v - bf2f(hi.y));
        v = x[(size_t)(b0 + 2) * K_ + k]; hi.z = f2bf(v); lo.z = f2bf(v - bf2f(hi.z));
        v = x[(size_t)(b0 + 3) * K_ + k]; hi.w = f2bf(v); lo.w = f2bf(v - bf2f(hi.w));
        ((ushort4*)Xt_hi)[(size_t)k * 64 + (t & 63)] = hi;
        ((ushort4*)Xt_lo)[(size_t)k * 64 + (t & 63)] = lo;
    }
    for (int t = gthread; t < I_ * J_; t += NTHR) blog[t] = 0.f;
    grid_barrier(bar_count, bar_gen);

    for (int it = 0; it < 3; ++it) {
        // ---- gemm_s: S = X @ (c o W)^T, fp32-equiv via hi/lo splits.
        // Blocks 0..319 (waves 0..1279); softmax inlined per-block into LDS.
        if (blk < 320) {
            const int ks = blk / 40;          // uniform per block
            // c-stage: softmax for rows i = ks*144 .. +143
            for (int r = tid; r < 144; r += 256) {
                const float* br = blog + (size_t)(ks * 144 + r) * J_;
                float bv[J_];
                float mx = -1e30f;
                #pragma unroll
                for (int j = 0; j < J_; ++j) { bv[j] = br[j]; mx = fmaxf(mx, bv[j]); }
                float sum = 0.f;
                #pragma unroll
                for (int j = 0; j < J_; ++j) { bv[j] = __expf(bv[j] - mx); sum += bv[j]; }
                float inv = 1.f / sum;
                #pragma unroll
                for (int j = 0; j < J_; ++j) c_lds[r * J_ + j] = bv[j] * inv;
            }
            __syncthreads();

            const int wv   = blk * 4 + (tid >> 6);   // 0..1279
            const int tile = wv % 160;
            const int mb = tile / J_, nt = tile % J_;
            const int r = lane & 15, q = lane >> 4;
            const float* ap = x + (size_t)(mb * 16 + r) * K_ + ks * KCHUNK + 8 * q;
            const float* wp = W + (((size_t)(ks * 144 + q) * J_ + nt) * DOUT_ + r) * DIN_;
            floatx4 acc = {0.f, 0.f, 0.f, 0.f};
            #pragma unroll 4
            for (int s = 0; s < KSTEPS; ++s) {
                float4 xa0 = *(const float4*)(ap + s * 32);
                float4 xa1 = *(const float4*)(ap + s * 32 + 4);
                float4 w0  = *(const float4*)(wp + (size_t)s * 4 * J_ * DOUT_ * DIN_);
                float4 w1  = *(const float4*)(wp + (size_t)s * 4 * J_ * DOUT_ * DIN_ + 4);
                float cs   = c_lds[(4 * s + q) * J_ + nt];
                float xv[8]  = {xa0.x, xa0.y, xa0.z, xa0.w, xa1.x, xa1.y, xa1.z, xa1.w};
                float wvv[8] = {w0.x, w0.y, w0.z, w0.w, w1.x, w1.y, w1.z, w1.w};
                bf16x8 ah, al, bh, bl;
                #pragma unroll
                for (int e = 0; e < 8; ++e) {
                    float xe = xv[e];
                    __bf16 h = (__bf16)xe;
                    ah[e] = h;
                    al[e] = (__bf16)(xe - (float)h);
                    float pe = wvv[e] * cs;
                    __bf16 g = (__bf16)pe;
                    bh[e] = g;
                    bl[e] = (__bf16)(pe - (float)g);
                }
                acc = __builtin_amdgcn_mfma_f32_16x16x32_bf16(ah, bh, acc, 0, 0, 0);
                acc = __builtin_amdgcn_mfma_f32_16x16x32_bf16(al, bh, acc, 0, 0, 0);
                acc = __builtin_amdgcn_mfma_f32_16x16x32_bf16(ah, bl, acc, 0, 0, 0);
            }
            ((floatx4*)P)[(size_t)(ks * 160 + tile) * 64 + lane] = acc;
        }
        grid_barrier(bar_count, bar_gen);

        // ---- reduce split-K + squash; emit s_out fp32 + Sbt hi/lo ----
        if (gthread < B_ * N_) {
            int t = gthread;
            int b  = t / N_;
            int rr = t - b * N_;
            int j = rr >> 4, o = rr & 15;
            int tile = (b >> 4) * J_ + j;
            int lane_c = (((b & 15) >> 2) << 4) | o;  // C/D: col=lane&15, row=quad*4+reg
            int reg  = b & 3;
            float v = 0.f;
            #pragma unroll
            for (int ks = 0; ks < NSPLIT; ++ks)
                v += P[((size_t)(ks * 160 + tile) * 64 + lane_c) * 4 + reg];
            float sq = v * v;
            #pragma unroll
            for (int off = 1; off < 16; off <<= 1)
                sq += __shfl_xor(sq, off, 16);
            float l2 = sqrtf(sq);
            float val = v * (l2 / (1.f + sq));
            s_out[t] = val;
            ushort_t hi = f2bf(val);
            Sbt_hi[(size_t)rr * B_ + b] = hi;
            Sbt_lo[(size_t)rr * B_ + b] = f2bf(val - bf2f(hi));
        }

        if (it < 2) {
            grid_barrier(bar_count, bar_gen);
            // ---- b-update GEMM: hi/lo both sides, fp32 W contraction ----
            for (int item = waveid; item < 5760; item += 2048) {
                int mt = item / J_;
                int j  = item - mt * J_;
                int r = lane & 15, q = lane >> 4;
                size_t aoff = (size_t)(mt * 16 + r) * B_ + 8 * q;
                size_t boff = (size_t)(j * 16 + r) * B_ + 8 * q;
                floatx4 acc = {0.f, 0.f, 0.f, 0.f};
                #pragma unroll
                for (int s = 0; s < B_ / 32; ++s) {
                    bf16x8 ah = *(const bf16x8*)(Xt_hi + aoff + s * 32);
                    bf16x8 al = *(const bf16x8*)(Xt_lo + aoff + s * 32);
                    bf16x8 bh = *(const bf16x8*)(Sbt_hi + boff + s * 32);
                    bf16x8 bl = *(const bf16x8*)(Sbt_lo + boff + s * 32);
                    acc = __builtin_amdgcn_mfma_f32_16x16x32_bf16(ah, bh, acc, 0, 0, 0);
                    acc = __builtin_amdgcn_mfma_f32_16x16x32_bf16(al, bh, acc, 0, 0, 0);
                    acc = __builtin_amdgcn_mfma_f32_16x16x32_bf16(ah, bl, acc, 0, 0, 0);
                }
                int i  = mt * 2 + (q >> 1);
                int d0 = (q & 1) * 4;
                int o  = lane & 15;
                const float4 w4 = *(const float4*)(W +
                    ((((size_t)i * J_ + j) * DOUT_ + o) * DIN_ + d0));
                float val = acc[0] * w4.x + acc[1] * w4.y + acc[2] * w4.z + acc[3] * w4.w;
                #pragma unroll
                for (int off = 1; off < 32; off <<= 1)
                    val += __shfl_xor(val, off, 32);
                if ((lane & 31) == 0)
                    blog[(size_t)(mt * 2 + (lane >> 5)) * J_ + j] += val;  // unique writer
            }
            grid_barrier(bar_count, bar_gen);
        }
    }
}

// ---------------------------------------------------------------------------
extern "C" void kernel_launch(void* const* d_in, const int* in_sizes, int n_in,
                              void* d_out, int out_size, void* d_ws, size_t ws_size,
                              hipStream_t stream)
{
    const float* x = (const float*)d_in[0];   // [B, I, DIN]
    const float* W = (const float*)d_in[1];   // [I, J, DOUT, DIN]
    float* s_out = (float*)d_out;             // [B, J, DOUT]

    char* ws = (char*)d_ws;
    ushort_t* Xt_hi  = (ushort_t*)(ws);                    //  4,718,592 B
    ushort_t* Xt_lo  = (ushort_t*)(ws + 4718592);          //  4,718,592 B
    ushort_t* Sbt_hi = (ushort_t*)(ws + 9437184);          //     81,920 B
    ushort_t* Sbt_lo = (ushort_t*)(ws + 9519104);          //     81,920 B
    float*    P      = (float*)   (ws + 9601024);          //  1,310,720 B
    float*    blog   = (float*)   (ws + 10911744);         //     46,080 B
    unsigned* bar    = (unsigned*)(ws + 10957824);         //          8 B

    hipMemsetAsync(bar, 0, 2 * sizeof(unsigned), stream);
    capsule_fused_kernel<<<NBLK, 256, 0, stream>>>(x, W, s_out, Xt_hi, Xt_lo,
                                                   Sbt_hi, Sbt_lo, P, blog, bar);
}

// Round 9
// 181.525 us; speedup vs baseline: 6.1908x; 6.1908x over previous
//
#include <hip/hip_runtime.h>
#include <math.h>

typedef unsigned short ushort_t;
typedef __attribute__((ext_vector_type(8))) __bf16 bf16x8;
typedef __attribute__((ext_vector_type(4))) float floatx4;

#define B_    256
#define I_    1152
#define J_    10
#define DIN_  8
#define DOUT_ 16
#define K_    (I_*DIN_)     // 9216
#define N_    (J_*DOUT_)    // 160
#define NSPLIT 32
#define KCHUNK (K_/NSPLIT)  // 288 (36 i's per split)
#define KSTEPS (KCHUNK/32)  // 9

static __device__ __forceinline__ ushort_t f2bf(float f) {
    unsigned int u = __float_as_uint(f);
    u += 0x7fffu + ((u >> 16) & 1u);     // RNE
    return (ushort_t)(u >> 16);
}
static __device__ __forceinline__ float bf2f(ushort_t h) {
    return __uint_as_float(((unsigned int)h) << 16);
}

// --- one-time prep: Xt hi/lo bf16 [K][B] (transpose + Dekker split) + zero blog
__global__ __launch_bounds__(256)
void prep_xt_kernel(const float* __restrict__ x, ushort_t* __restrict__ Xt_hi,
                    ushort_t* __restrict__ Xt_lo, float* __restrict__ blog)
{
    int t = blockIdx.x * 256 + threadIdx.x;       // 589824
    if (t < I_ * J_) blog[t] = 0.f;
    int k  = t >> 6;
    int b0 = (t & 63) * 4;
    ushort4 hi, lo;
    float v;
    v = x[(size_t)(b0 + 0) * K_ + k]; hi.x = f2bf(v); lo.x = f2bf(v - bf2f(hi.x));
    v = x[(size_t)(b0 + 1) * K_ + k]; hi.y = f2bf(v); lo.y = f2bf(v - bf2f(hi.y));
    v = x[(size_t)(b0 + 2) * K_ + k]; hi.z = f2bf(v); lo.z = f2bf(v - bf2f(hi.z));
    v = x[(size_t)(b0 + 3) * K_ + k]; hi.w = f2bf(v); lo.w = f2bf(v - bf2f(hi.w));
    ((ushort4*)Xt_hi)[(size_t)k * 64 + (t & 63)] = hi;
    ((ushort4*)Xt_lo)[(size_t)k * 64 + (t & 63)] = lo;
}

// --- s-GEMM: S = X @ (c ∘ W)^T, M=256 N=160 K=9216, split-K=32, softmax fused
// (block-local: all 4 waves of a block share one ks => one 36-row softmax in LDS).
// Both operands fp32->Dekker-split in-register; 3 MFMAs/step (fp32-equivalent).
__global__ __launch_bounds__(256)
void gemm_s_kernel(const float* __restrict__ x, const float* __restrict__ W,
                   const float* __restrict__ blog, floatx4* __restrict__ P)
{
    const int tid = threadIdx.x;
    const int blk = blockIdx.x;          // 0..1279
    const int lane = tid & 63;
    const int ks  = blk / 40;            // uniform per block (wv/160 == blk/40)

    __shared__ float c_lds[KCHUNK / DIN_ * J_];   // 36*10 floats

    // softmax for rows i = ks*36 .. +35
    if (tid < 36) {
        const float* br = blog + (size_t)(ks * 36 + tid) * J_;
        float bv[J_];
        float mx = -1e30f;
        #pragma unroll
        for (int j = 0; j < J_; ++j) { bv[j] = br[j]; mx = fmaxf(mx, bv[j]); }
        float sum = 0.f;
        #pragma unroll
        for (int j = 0; j < J_; ++j) { bv[j] = __expf(bv[j] - mx); sum += bv[j]; }
        float inv = 1.f / sum;
        #pragma unroll
        for (int j = 0; j < J_; ++j) c_lds[tid * J_ + j] = bv[j] * inv;
    }
    __syncthreads();

    const int wv   = blk * 4 + (tid >> 6);   // 0..5119
    const int tile = wv % 160;
    const int mb = tile / J_, nt = tile % J_;
    const int r = lane & 15, q = lane >> 4;
    const float* ap = x + (size_t)(mb * 16 + r) * K_ + ks * KCHUNK + 8 * q;
    // B row (j=nt, o=r); k-frag covers i = ks*36 + 4s + q, d=0..7
    const float* wp = W + (((size_t)(ks * 36 + q) * J_ + nt) * DOUT_ + r) * DIN_;
    floatx4 acc = {0.f, 0.f, 0.f, 0.f};
    #pragma unroll
    for (int s = 0; s < KSTEPS; ++s) {
        float4 xa0 = *(const float4*)(ap + s * 32);
        float4 xa1 = *(const float4*)(ap + s * 32 + 4);
        float4 w0  = *(const float4*)(wp + (size_t)s * 4 * J_ * DOUT_ * DIN_);
        float4 w1  = *(const float4*)(wp + (size_t)s * 4 * J_ * DOUT_ * DIN_ + 4);
        float cs   = c_lds[(4 * s + q) * J_ + nt];
        float xv[8]  = {xa0.x, xa0.y, xa0.z, xa0.w, xa1.x, xa1.y, xa1.z, xa1.w};
        float wvv[8] = {w0.x, w0.y, w0.z, w0.w, w1.x, w1.y, w1.z, w1.w};
        bf16x8 ah, al, bh, bl;
        #pragma unroll
        for (int e = 0; e < 8; ++e) {
            float xe = xv[e];
            __bf16 h = (__bf16)xe;
            ah[e] = h;
            al[e] = (__bf16)(xe - (float)h);
            float pe = wvv[e] * cs;
            __bf16 g = (__bf16)pe;
            bh[e] = g;
            bl[e] = (__bf16)(pe - (float)g);
        }
        acc = __builtin_amdgcn_mfma_f32_16x16x32_bf16(ah, bh, acc, 0, 0, 0);
        acc = __builtin_amdgcn_mfma_f32_16x16x32_bf16(al, bh, acc, 0, 0, 0);
        acc = __builtin_amdgcn_mfma_f32_16x16x32_bf16(ah, bl, acc, 0, 0, 0);
    }
    P[(size_t)(ks * 160 + tile) * 64 + lane] = acc;
}

// --- reduce split-K partials + squash; emit s_out fp32 and Sbt hi/lo bf16 [(j,o)][b]
__global__ __launch_bounds__(256)
void reduce_squash_kernel(const float* __restrict__ P, float* __restrict__ s_out,
                          ushort_t* __restrict__ Sbt_hi, ushort_t* __restrict__ Sbt_lo)
{
    int t = blockIdx.x * 256 + threadIdx.x;   // 40960
    int b  = t / N_;
    int rr = t - b * N_;                      // jo
    int j = rr >> 4, o = rr & 15;
    int tile = (b >> 4) * J_ + j;
    int lane = (((b & 15) >> 2) << 4) | o;    // C/D: col=lane&15, row=(lane>>4)*4+reg
    int reg  = b & 3;
    float v = 0.f;
    #pragma unroll
    for (int ks = 0; ks < NSPLIT; ++ks)
        v += P[((size_t)(ks * 160 + tile) * 64 + lane) * 4 + reg];
    float sq = v * v;
    #pragma unroll
    for (int off = 1; off < 16; off <<= 1)
        sq += __shfl_xor(sq, off, 16);
    float l2 = sqrtf(sq);
    float val = v * (l2 / (1.f + sq));
    s_out[t] = val;
    ushort_t hi = f2bf(val);
    Sbt_hi[(size_t)rr * B_ + b] = hi;
    Sbt_lo[(size_t)rr * B_ + b] = f2bf(val - bf2f(hi));
}

// --- b-update GEMM: T2 = Xt @ S' (M=9216 N=160 K=256), hi/lo split both sides,
// contracted with fp32 W in-register. Unique (i,j) writer per half-wave.
__global__ __launch_bounds__(256)
void gemm_bupd_kernel(const ushort_t* __restrict__ Xt_hi, const ushort_t* __restrict__ Xt_lo,
                      const ushort_t* __restrict__ Sbt_hi, const ushort_t* __restrict__ Sbt_lo,
                      const float* __restrict__ W, float* __restrict__ blog)
{
    int wv   = blockIdx.x * 4 + (threadIdx.x >> 6);   // 0..5759
    int lane = threadIdx.x & 63;
    int mt = wv / J_;                                 // 0..575
    int j  = wv - mt * J_;
    int r = lane & 15, q = lane >> 4;
    size_t aoff = (size_t)(mt * 16 + r) * B_ + 8 * q;
    size_t boff = (size_t)(j * 16 + r) * B_ + 8 * q;
    floatx4 acc = {0.f, 0.f, 0.f, 0.f};
    #pragma unroll
    for (int s = 0; s < B_ / 32; ++s) {
        bf16x8 ah = *(const bf16x8*)(Xt_hi + aoff + s * 32);
        bf16x8 al = *(const bf16x8*)(Xt_lo + aoff + s * 32);
        bf16x8 bh = *(const bf16x8*)(Sbt_hi + boff + s * 32);
        bf16x8 bl = *(const bf16x8*)(Sbt_lo + boff + s * 32);
        acc = __builtin_amdgcn_mfma_f32_16x16x32_bf16(ah, bh, acc, 0, 0, 0);
        acc = __builtin_amdgcn_mfma_f32_16x16x32_bf16(al, bh, acc, 0, 0, 0);
        acc = __builtin_amdgcn_mfma_f32_16x16x32_bf16(ah, bl, acc, 0, 0, 0);
    }
    // rows q*4+reg -> i = mt*2 + (q>>1), d = (q&1)*4 + reg; col -> o = lane&15
    int i  = mt * 2 + (q >> 1);
    int d0 = (q & 1) * 4;
    int o  = lane & 15;
    const float4 w4 = *(const float4*)(W + ((((size_t)i * J_ + j) * DOUT_ + o) * DIN_ + d0));
    float val = acc[0] * w4.x + acc[1] * w4.y + acc[2] * w4.z + acc[3] * w4.w;
    #pragma unroll
    for (int off = 1; off < 32; off <<= 1)
        val += __shfl_xor(val, off, 32);
    if ((lane & 31) == 0)
        blog[(size_t)(mt * 2 + (lane >> 5)) * J_ + j] += val;   // unique writer
}

// ---------------------------------------------------------------------------
extern "C" void kernel_launch(void* const* d_in, const int* in_sizes, int n_in,
                              void* d_out, int out_size, void* d_ws, size_t ws_size,
                              hipStream_t stream)
{
    const float* x = (const float*)d_in[0];   // [B, I, DIN]
    const float* W = (const float*)d_in[1];   // [I, J, DOUT, DIN]
    float* s_out = (float*)d_out;             // [B, J, DOUT]

    char* ws = (char*)d_ws;
    ushort_t* Xt_hi  = (ushort_t*)(ws);                    //  4,718,592 B
    ushort_t* Xt_lo  = (ushort_t*)(ws + 4718592);          //  4,718,592 B
    ushort_t* Sbt_hi = (ushort_t*)(ws + 9437184);          //     81,920 B
    ushort_t* Sbt_lo = (ushort_t*)(ws + 9519104);          //     81,920 B
    float*    P      = (float*)   (ws + 9601024);          //  5,242,880 B
    float*    blog   = (float*)   (ws + 14843904);         //     46,080 B  (end ~14.9 MB)

    prep_xt_kernel<<<2304, 256, 0, stream>>>(x, Xt_hi, Xt_lo, blog);

    for (int it = 0; it < 3; ++it) {
        gemm_s_kernel<<<1280, 256, 0, stream>>>(x, W, blog, (floatx4*)P);
        reduce_squash_kernel<<<160, 256, 0, stream>>>(P, s_out, Sbt_hi, Sbt_lo);
        if (it < 2)
            gemm_bupd_kernel<<<1440, 256, 0, stream>>>(Xt_hi, Xt_lo, Sbt_hi, Sbt_lo,
                                                       W, blog);
    }
}